// Round 19
// baseline (697.434 us; speedup 1.0000x reference)
//
#include <hip/hip_runtime.h>
#include <math.h>

#define S_LEN   1023
#define BATCH_N 4
#define DMODEL  512
#define NHEAD   8
#define DHEAD   64
#define DINNER  2048
#define NLAYER  4
#define RAWLEN  8192
#define POOLW   8
#define KERNW   9
#define RLEN    (2*S_LEN-1)   /* 2045 */
#define MROWS   (S_LEN*BATCH_N) /* 4092 */

using bf16x8 = __attribute__((ext_vector_type(8))) short;
using f32x4  = __attribute__((ext_vector_type(4))) float;

__device__ __forceinline__ unsigned short f2bf(float f) {
    union { float f; unsigned int u; } v; v.f = f;
    unsigned int u = v.u;
    return (unsigned short)((u + 0x7fffu + ((u >> 16) & 1u)) >> 16);
}
__device__ __forceinline__ float bf2f(unsigned short h) {
    union { unsigned int u; float f; } v; v.u = ((unsigned int)h) << 16;
    return v.f;
}

// async 16B global -> LDS (dest = wave-uniform base + lane*16)
__device__ __forceinline__ void gload_lds16(const void* g, void* l) {
    using gvoid = const __attribute__((address_space(1))) void;
    using lvoid = __attribute__((address_space(3))) void;
    gvoid* gp = reinterpret_cast<gvoid*>(reinterpret_cast<unsigned long long>(g));
    lvoid* lp = reinterpret_cast<lvoid*>((unsigned int)reinterpret_cast<unsigned long long>(l));
    __builtin_amdgcn_global_load_lds(gp, lp, 16, 0, 0);
}

// ---------------- conv + relu + pool8 -> core f32 + bf16 ----------------
__global__ __launch_bounds__(512) void conv_pool_kernel(
    const float* __restrict__ sig, const float* __restrict__ cw,
    const float* __restrict__ cb, float* __restrict__ core,
    unsigned short* __restrict__ core_bf)
{
    int s = blockIdx.x, b = blockIdx.y, d = threadIdx.x;
    __shared__ float sseg[POOLW + KERNW - 1];
    if (d < POOLW + KERNW - 1) sseg[d] = sig[b*RAWLEN + s*POOLW + d];
    __syncthreads();
    float w[KERNW];
#pragma unroll
    for (int k = 0; k < KERNW; k++) w[k] = cw[k*DMODEL + d];
    float bias = cb[d];
    float acc = 0.f;
#pragma unroll
    for (int p = 0; p < POOLW; p++) {
        float c = bias;
#pragma unroll
        for (int k = 0; k < KERNW; k++) c = fmaf(sseg[p+k], w[k], c);
        acc += fmaxf(c, 0.f);
    }
    float v = acc * (1.0f/POOLW);
    core[(s*BATCH_N + b)*DMODEL + d] = v;
    core_bf[(s*BATCH_N + b)*DMODEL + d] = f2bf(v);
}

// ---------------- positional embedding -> bf16 ----------------
__global__ __launch_bounds__(512) void posemb_kernel(unsigned short* __restrict__ pe)
{
    int j = blockIdx.x, d = threadIdx.x;
    float pos = (float)(S_LEN - 1 - j);
    int i = (d < 256) ? d : d - 256;
    float invf = exp2f(-(float)i * (13.287712f/256.0f));
    float a = pos * invf;
    pe[j*DMODEL + d] = f2bf((d < 256) ? __sinf(a) : __cosf(a));
}

// ---------------- fused per-layer weight transposes: W[K][N] f32 -> Wt[N][K] bf16 ----------------
__global__ __launch_bounds__(256) void transpose_all_kernel(
    const float* __restrict__ qw, const float* __restrict__ rw,
    const float* __restrict__ ow, const float* __restrict__ f1,
    const float* __restrict__ f2,
    unsigned short* __restrict__ qT, unsigned short* __restrict__ rT,
    unsigned short* __restrict__ oT, unsigned short* __restrict__ f1T,
    unsigned short* __restrict__ f2T)
{
    int id = blockIdx.x;
    const float* W; unsigned short* Wt; int K, N, bx, by;
    if (id < 768)       { W = qw;  Wt = qT;  K = 512;  N = 1536; bx = id % 48; by = id / 48; }
    else if (id < 1024) { id -= 768;  W = rw;  Wt = rT;  K = 512;  N = 512;  bx = id % 16; by = id / 16; }
    else if (id < 1280) { id -= 1024; W = ow;  Wt = oT;  K = 512;  N = 512;  bx = id % 16; by = id / 16; }
    else if (id < 2304) { id -= 1280; W = f1;  Wt = f1T; K = 512;  N = 2048; bx = id % 64; by = id / 64; }
    else                { id -= 2304; W = f2;  Wt = f2T; K = 2048; N = 512;  bx = id % 16; by = id / 16; }

    __shared__ float L[32][33];
    int n0 = bx*32, k0 = by*32;
    int t = threadIdx.x;
    int kk = t>>3, nq = (t&7)*4;
    float4 v = *reinterpret_cast<const float4*>(&W[(size_t)(k0+kk)*N + n0 + nq]);
    L[kk][nq+0]=v.x; L[kk][nq+1]=v.y; L[kk][nq+2]=v.z; L[kk][nq+3]=v.w;
    __syncthreads();
    int nn = t>>3, kq = (t&7)*4;
    ushort4 o;
    o.x = f2bf(L[kq+0][nn]); o.y = f2bf(L[kq+1][nn]);
    o.z = f2bf(L[kq+2][nn]); o.w = f2bf(L[kq+3][nn]);
    *reinterpret_cast<ushort4*>(&Wt[(size_t)(n0+nn)*K + k0 + kq]) = o;
}

// ---------------- MFMA GEMM body (shared): A(MxK bf16) @ Bt(NxK bf16)^T -> C ----------------
template<int BN, bool ACCUM, bool BIAS, bool RELU, bool WF32, bool WBF>
__device__ __forceinline__ void gemm_body(
    const unsigned short* __restrict__ A, const unsigned short* __restrict__ Bt,
    const float* __restrict__ bias, float* __restrict__ C,
    unsigned short* __restrict__ Cb, int M, int N, int K, int bm, int bn,
    unsigned short* As, unsigned short* Bs)
{
    constexpr int MF = (BN == 128) ? 4 : 2;
    int tid = threadIdx.x, lane = tid & 63, wid = tid >> 6;

    f32x4 acc[MF][4];
#pragma unroll
    for (int m=0;m<MF;m++)
#pragma unroll
        for (int n=0;n<4;n++) acc[m][n] = (f32x4){0.f,0.f,0.f,0.f};

    int r0 = wid*16 + (lane>>2);
    int slot = (lane&3)*8;
    int ga0 = bm + r0;      if (ga0 > M-1) ga0 = M-1;
    int ga1 = bm + r0 + 64; if (ga1 > M-1) ga1 = M-1;
    const unsigned short* pA0 = A  + (size_t)ga0*K + slot;
    const unsigned short* pA1 = A  + (size_t)ga1*K + slot;
    const unsigned short* pB0 = Bt + (size_t)(bn + r0)*K + slot;
    const unsigned short* pB1 = (BN==128) ? Bt + (size_t)(bn + r0 + 64)*K + slot : nullptr;
    char* lA0 = (char*)As + wid*1024;
    char* lA1 = (char*)As + (wid+4)*1024;
    char* lB0 = (char*)Bs + wid*1024;
    char* lB1 = (char*)Bs + (wid+4)*1024;

    int ar = (BN==128 ? (wid>>1)*64 : wid*32) + (lane&15);
    int br = (BN==128 ? (wid&1)*64 : 0) + (lane&15);
    int kc = (lane>>4)*8;

    for (int k0 = 0; k0 < K; k0 += 32) {
        __syncthreads();
        gload_lds16(pA0, lA0);
        gload_lds16(pA1, lA1);
        gload_lds16(pB0, lB0);
        if (BN == 128) gload_lds16(pB1, lB1);
        pA0 += 32; pA1 += 32; pB0 += 32; if (BN==128) pB1 += 32;
        __syncthreads();
        bf16x8 a[MF], b[4];
#pragma unroll
        for (int m=0;m<MF;m++) a[m] = *reinterpret_cast<const bf16x8*>(&As[(ar + m*16)*32 + kc]);
#pragma unroll
        for (int n=0;n<4;n++) b[n] = *reinterpret_cast<const bf16x8*>(&Bs[(br + n*16)*32 + kc]);
#pragma unroll
        for (int m=0;m<MF;m++)
#pragma unroll
            for (int n=0;n<4;n++)
                acc[m][n] = __builtin_amdgcn_mfma_f32_16x16x32_bf16(a[m], b[n], acc[m][n], 0,0,0);
    }

    int col0 = bn + (BN==128 ? (wid&1)*64 : 0) + (lane&15);
    int rbase = bm + (BN==128 ? (wid>>1)*64 : wid*32) + (lane>>4)*4;
#pragma unroll
    for (int m=0;m<MF;m++) {
#pragma unroll
        for (int n=0;n<4;n++) {
            int col = col0 + n*16;
            float bv = BIAS ? bias[col] : 0.f;
#pragma unroll
            for (int r=0;r<4;r++) {
                int row = rbase + m*16 + r;
                if (row < M) {
                    float v = acc[m][n][r] + bv;
                    if (RELU) v = fmaxf(v, 0.f);
                    size_t off = (size_t)row*N + col;
                    if (ACCUM) v += C[off];
                    if (WF32) C[off] = v;
                    if (WBF)  Cb[off] = f2bf(v);
                }
            }
        }
    }
}

template<int BN, bool ACCUM, bool BIAS, bool RELU, bool WF32, bool WBF>
__global__ __launch_bounds__(256) void gemm_mfma(
    const unsigned short* __restrict__ A, const unsigned short* __restrict__ Bt,
    const float* __restrict__ bias, float* __restrict__ C,
    unsigned short* __restrict__ Cb, int M, int N, int K)
{
    __shared__ unsigned short As[128*32];
    __shared__ unsigned short Bs[BN*32];
    gemm_body<BN,ACCUM,BIAS,RELU,WF32,WBF>(A, Bt, bias, C, Cb, M, N, K,
        blockIdx.y*128, blockIdx.x*BN, As, Bs);
}

// fused qkv (x<24) + rk (x>=24, y<16) in one dispatch
__global__ __launch_bounds__(256) void gemm_qkvrk_kernel(
    const unsigned short* __restrict__ core_bf, const unsigned short* __restrict__ qkvT,
    unsigned short* __restrict__ heads,
    const unsigned short* __restrict__ pe_bf, const unsigned short* __restrict__ rwT,
    unsigned short* __restrict__ rk_bf)
{
    __shared__ unsigned short As[128*32];
    __shared__ unsigned short Bs[64*32];
    if (blockIdx.x < 24) {
        gemm_body<64,false,false,false,false,true>(core_bf, qkvT, nullptr, nullptr, heads,
            MROWS, 3*DMODEL, DMODEL, blockIdx.y*128, blockIdx.x*64, As, Bs);
    } else {
        if (blockIdx.y >= 16) return;
        gemm_body<64,false,false,false,false,true>(pe_bf, rwT, nullptr, nullptr, rk_bf,
            RLEN, DMODEL, DMODEL, blockIdx.y*128, (blockIdx.x-24)*64, As, Bs);
    }
}

// ---------------- 64x64-tile MFMA GEMM (narrow-N accumulating cases) ----------------
template<bool ACCUM, bool BIAS, bool RELU, bool WF32, bool WBF>
__global__ __launch_bounds__(256) void gemm_mfma64(
    const unsigned short* __restrict__ A, const unsigned short* __restrict__ Bt,
    const float* __restrict__ bias, float* __restrict__ C,
    unsigned short* __restrict__ Cb, int M, int N, int K)
{
    __shared__ unsigned short As[64*32];
    __shared__ unsigned short Bs[64*32];
    int bm = blockIdx.y * 64, bn = blockIdx.x * 64;
    int tid = threadIdx.x, lane = tid & 63, wid = tid >> 6;
    int wr = wid >> 1, wc = wid & 1;

    f32x4 acc[2][2];
#pragma unroll
    for (int m=0;m<2;m++)
#pragma unroll
        for (int n=0;n<2;n++) acc[m][n] = (f32x4){0.f,0.f,0.f,0.f};

    int r0 = wid*16 + (lane>>2);
    int slot = (lane&3)*8;
    int ga = bm + r0; if (ga > M-1) ga = M-1;
    const unsigned short* pA = A  + (size_t)ga*K + slot;
    const unsigned short* pB = Bt + (size_t)(bn + r0)*K + slot;
    char* lA = (char*)As + wid*1024;
    char* lB = (char*)Bs + wid*1024;

    int ar = wr*32 + (lane&15);
    int br = wc*32 + (lane&15);
    int kc = (lane>>4)*8;

    for (int k0 = 0; k0 < K; k0 += 32) {
        __syncthreads();
        gload_lds16(pA, lA);
        gload_lds16(pB, lB);
        pA += 32; pB += 32;
        __syncthreads();
        bf16x8 a[2], b[2];
#pragma unroll
        for (int m=0;m<2;m++) a[m] = *reinterpret_cast<const bf16x8*>(&As[(ar + m*16)*32 + kc]);
#pragma unroll
        for (int n=0;n<2;n++) b[n] = *reinterpret_cast<const bf16x8*>(&Bs[(br + n*16)*32 + kc]);
#pragma unroll
        for (int m=0;m<2;m++)
#pragma unroll
            for (int n=0;n<2;n++)
                acc[m][n] = __builtin_amdgcn_mfma_f32_16x16x32_bf16(a[m], b[n], acc[m][n], 0,0,0);
    }

    int col0 = bn + wc*32 + (lane&15);
    int rbase = bm + wr*32 + (lane>>4)*4;
#pragma unroll
    for (int m=0;m<2;m++) {
#pragma unroll
        for (int n=0;n<2;n++) {
            int col = col0 + n*16;
            float bv = BIAS ? bias[col] : 0.f;
#pragma unroll
            for (int r=0;r<4;r++) {
                int row = rbase + m*16 + r;
                if (row < M) {
                    float v = acc[m][n][r] + bv;
                    if (RELU) v = fmaxf(v, 0.f);
                    size_t off = (size_t)row*N + col;
                    if (ACCUM) v += C[off];
                    if (WF32) C[off] = v;
                    if (WBF)  Cb[off] = f2bf(v);
                }
            }
        }
    }
}

// ---------------- MFMA flash attention (R8 proven + s_setprio around MFMA phases) ----------------
#define TI 32
#define TJ 32
#define PSTR 40   /* bf16 row stride Pb */
#define ACSTR 36  /* f32 row stride Sac */
#define BDSTR 68  /* f32 row stride Sbd */

__global__ __launch_bounds__(256) void attn_mfma_kernel(
    const unsigned short* __restrict__ heads, // (S,B,1536) bf16
    const unsigned short* __restrict__ rk,    // (2045,512) bf16
    const float* __restrict__ rwb, const float* __restrict__ rrb,
    unsigned short* __restrict__ av)          // (S,B,512) bf16
{
    int i0 = blockIdx.x * TI;
    int bn = blockIdx.y; int b = bn >> 3, n = bn & 7;
    int tid = threadIdx.x, lane = tid & 63, wid = tid >> 6;
    int mi = wid >> 1;          // i-row block (0/1)
    int half = wid & 1;         // col-half assignment
    int kc = (lane>>4)*8;
    int l15 = lane & 15;

    __shared__ float Sac[TI*ACSTR];
    __shared__ float Sbd[TI*BDSTR];
    __shared__ unsigned short Pb[TI*PSTR];
    __shared__ float mrow[TI], lrow[TI], frow[TI];

    const int base0 = (S_LEN-1) - i0 - (TI-1);   // rk global row at window offset 0

    // ---- Q fragments direct from global, biases folded ----
    bf16x8 qwf0, qwf1, qrf0, qrf1;
    {
        int gi = i0 + mi*16 + l15; if (gi > S_LEN-1) gi = S_LEN-1;
        const unsigned short* qb = heads + (size_t)(gi*BATCH_N + b)*1536 + n*64;
        bf16x8 u0 = *reinterpret_cast<const bf16x8*>(qb + kc);
        bf16x8 u1 = *reinterpret_cast<const bf16x8*>(qb + 32 + kc);
#pragma unroll
        for (int e=0;e<8;e++) {
            float f0 = bf2f((unsigned short)u0[e]);
            float f1 = bf2f((unsigned short)u1[e]);
            qwf0[e] = (short)f2bf(f0 + rwb[n*64 + kc + e]);
            qrf0[e] = (short)f2bf(f0 + rrb[n*64 + kc + e]);
            qwf1[e] = (short)f2bf(f1 + rwb[n*64 + 32 + kc + e]);
            qrf1[e] = (short)f2bf(f1 + rrb[n*64 + 32 + kc + e]);
        }
    }
    if (tid < TI) { mrow[tid] = -1e30f; lrow[tid] = 0.f; }

    f32x4 Oa[2];
    Oa[0] = (f32x4){0.f,0.f,0.f,0.f};
    Oa[1] = (f32x4){0.f,0.f,0.f,0.f};

    int rw = mi*16 + (lane>>4)*4;

    for (int t = 0; t < 32; t++) {
        int j0 = t * TJ;
        __syncthreads();   // separates softmax(t-1) Sbd reads / PV(t-1) Pb reads from writes below

        __builtin_amdgcn_s_setprio(1);
        // ---- AC scores: B-frag = K rows direct from global ----
        {
            int gj = j0 + half*16 + l15; if (gj > S_LEN-1) gj = S_LEN-1;
            const unsigned short* kb = heads + (size_t)(gj*BATCH_N + b)*1536 + 512 + n*64;
            bf16x8 kf0 = *reinterpret_cast<const bf16x8*>(kb + kc);
            bf16x8 kf1 = *reinterpret_cast<const bf16x8*>(kb + 32 + kc);
            f32x4 s = (f32x4){0.f,0.f,0.f,0.f};
            s = __builtin_amdgcn_mfma_f32_16x16x32_bf16(qwf0, kf0, s, 0,0,0);
            s = __builtin_amdgcn_mfma_f32_16x16x32_bf16(qwf1, kf1, s, 0,0,0);
            int ci = half*16 + l15;
#pragma unroll
            for (int r=0;r<4;r++) Sac[(rw+r)*ACSTR + ci] = s[r];
        }
        // ---- BD scores into rolling Sbd cache (phys col = off & 63) ----
        if (t == 0) {
#pragma unroll
            for (int nn=0;nn<2;nn++) {
                int w = (half*2+nn)*16 + l15;         // phys col == off at t=0
                int gr = base0 + w; gr = gr < 0 ? 0 : (gr > RLEN-1 ? RLEN-1 : gr);
                const unsigned short* rb = rk + (size_t)gr*DMODEL + n*64;
                bf16x8 rf0 = *reinterpret_cast<const bf16x8*>(rb + kc);
                bf16x8 rf1 = *reinterpret_cast<const bf16x8*>(rb + 32 + kc);
                f32x4 sb = (f32x4){0.f,0.f,0.f,0.f};
                sb = __builtin_amdgcn_mfma_f32_16x16x32_bf16(qrf0, rf0, sb, 0,0,0);
                sb = __builtin_amdgcn_mfma_f32_16x16x32_bf16(qrf1, rf1, sb, 0,0,0);
#pragma unroll
                for (int r=0;r<4;r++) Sbd[(rw+r)*BDSTR + w] = sb[r];
            }
        } else {
            int pblk = ((t & 1) ? 0 : 2) + half;      // 2 new 16-col blocks this tile
            int w = pblk*16 + l15;                    // phys col
            int off = 32*(t+1) + (w & 31);            // window offset for this phys col
            int gr = base0 + off; gr = gr < 0 ? 0 : (gr > RLEN-1 ? RLEN-1 : gr);
            const unsigned short* rb = rk + (size_t)gr*DMODEL + n*64;
            bf16x8 rf0 = *reinterpret_cast<const bf16x8*>(rb + kc);
            bf16x8 rf1 = *reinterpret_cast<const bf16x8*>(rb + 32 + kc);
            f32x4 sb = (f32x4){0.f,0.f,0.f,0.f};
            sb = __builtin_amdgcn_mfma_f32_16x16x32_bf16(qrf0, rf0, sb, 0,0,0);
            sb = __builtin_amdgcn_mfma_f32_16x16x32_bf16(qrf1, rf1, sb, 0,0,0);
#pragma unroll
            for (int r=0;r<4;r++) Sbd[(rw+r)*BDSTR + w] = sb[r];
        }
        __builtin_amdgcn_s_setprio(0);
        __syncthreads();

        // ---- parallel online softmax: thread -> (row = tid>>3, 4 j at (tid&7)*4) ----
        {
            int r = tid>>3, seg = tid&7, jl = seg*4;
            float4 ac = *reinterpret_cast<const float4*>(&Sac[r*ACSTR + jl]);
            int cbase = 32*t + (TI-1) - r;    // phys col = (cbase + j) & 63
            float s0 = (ac.x + Sbd[r*BDSTR + ((cbase+jl+0)&63)]) * 0.125f;
            float s1 = (ac.y + Sbd[r*BDSTR + ((cbase+jl+1)&63)]) * 0.125f;
            float s2 = (ac.z + Sbd[r*BDSTR + ((cbase+jl+2)&63)]) * 0.125f;
            float s3 = (ac.w + Sbd[r*BDSTR + ((cbase+jl+3)&63)]) * 0.125f;
            int jg = j0 + jl;
            if (jg+0 >= S_LEN) s0 = -1e30f;
            if (jg+1 >= S_LEN) s1 = -1e30f;
            if (jg+2 >= S_LEN) s2 = -1e30f;
            if (jg+3 >= S_LEN) s3 = -1e30f;
            float tm = fmaxf(fmaxf(s0,s1), fmaxf(s2,s3));
            tm = fmaxf(tm, __shfl_xor(tm, 1));
            tm = fmaxf(tm, __shfl_xor(tm, 2));
            tm = fmaxf(tm, __shfl_xor(tm, 4));
            float mo = mrow[r];
            float mnew = fmaxf(mo, tm);
            float f = __expf(mo - mnew);
            float e0 = __expf(s0 - mnew), e1 = __expf(s1 - mnew);
            float e2 = __expf(s2 - mnew), e3 = __expf(s3 - mnew);
            float ssum = e0+e1+e2+e3;
            ssum += __shfl_xor(ssum, 1);
            ssum += __shfl_xor(ssum, 2);
            ssum += __shfl_xor(ssum, 4);
            if (seg == 0) {
                mrow[r] = mnew;
                lrow[r] = lrow[r]*f + ssum;
                frow[r] = f;
            }
            ushort4 pw;
            pw.x = f2bf(e0); pw.y = f2bf(e1); pw.z = f2bf(e2); pw.w = f2bf(e3);
            *reinterpret_cast<ushort4*>(&Pb[r*PSTR + jl]) = pw;
        }
        __syncthreads();

        // ---- PV: rescale O, then accumulate P @ V with V frags direct from global ----
        {
            float f0 = frow[rw+0], f1 = frow[rw+1], f2 = frow[rw+2], f3 = frow[rw+3];
#pragma unroll
            for (int nn=0;nn<2;nn++) {
                Oa[nn][0] *= f0; Oa[nn][1] *= f1; Oa[nn][2] *= f2; Oa[nn][3] *= f3;
            }
            bf16x8 pf = *reinterpret_cast<const bf16x8*>(&Pb[(mi*16 + l15)*PSTR + kc]);
            const unsigned short* vb = heads + 1024 + n*64;
            __builtin_amdgcn_s_setprio(1);
#pragma unroll
            for (int nn=0;nn<2;nn++) {
                int d = (half*2+nn)*16 + l15;
                bf16x8 vf;
#pragma unroll
                for (int e=0;e<8;e++) {
                    int gj = j0 + kc + e; if (gj > S_LEN-1) gj = S_LEN-1;
                    vf[e] = (short)vb[(size_t)(gj*BATCH_N + b)*1536 + d];
                }
                Oa[nn] = __builtin_amdgcn_mfma_f32_16x16x32_bf16(pf, vf, Oa[nn], 0,0,0);
            }
            __builtin_amdgcn_s_setprio(0);
        }
    }
    __syncthreads();

    // ---- epilogue ----
    {
        float linv[4];
#pragma unroll
        for (int r=0;r<4;r++) linv[r] = 1.0f / lrow[rw+r];
#pragma unroll
        for (int nn=0;nn<2;nn++) {
            int d = (half*2+nn)*16 + l15;
#pragma unroll
            for (int r=0;r<4;r++) {
                int gi = i0 + rw + r;
                if (gi < S_LEN)
                    av[(size_t)(gi*BATCH_N + b)*DMODEL + n*64 + d] = f2bf(Oa[nn][r]*linv[r]);
            }
        }
    }
}

// ---------------- final classifier (f32) ----------------
__global__ __launch_bounds__(64) void final_kernel(
    const float* __restrict__ core, const float* __restrict__ fcw,
    const float* __restrict__ fcb, float* __restrict__ out)
{
    int idx = blockIdx.x;
    int b = idx / 10, c = idx % 10;
    int lane = threadIdx.x;
    const float* row = &core[(size_t)((S_LEN-1)*BATCH_N + b)*DMODEL];
    float acc = 0.f;
    for (int d = lane; d < DMODEL; d += 64)
        acc = fmaf(row[d], fcw[d*10 + c], acc);
#pragma unroll
    for (int off = 32; off; off >>= 1) acc += __shfl_xor(acc, off);
    if (lane == 0) out[b*10 + c] = acc + fcb[c];
}

extern "C" void kernel_launch(void* const* d_in, const int* in_sizes, int n_in,
                              void* d_out, int out_size, void* d_ws, size_t ws_size,
                              hipStream_t stream)
{
    const float* sig   = (const float*)d_in[0];
    const float* cw    = (const float*)d_in[1];
    const float* cb    = (const float*)d_in[2];
    const float* qkv_w = (const float*)d_in[3];
    const float* r_w   = (const float*)d_in[4];
    const float* o_w   = (const float*)d_in[5];
    const float* ff1_w = (const float*)d_in[6];
    const float* ff1_b = (const float*)d_in[7];
    const float* ff2_w = (const float*)d_in[8];
    const float* ff2_b = (const float*)d_in[9];
    const float* rwb   = (const float*)d_in[10];
    const float* rrb   = (const float*)d_in[11];
    const float* fcw   = (const float*)d_in[12];
    const float* fcb   = (const float*)d_in[13];
    float* out = (float*)d_out;

    // workspace layout
    float* core = (float*)d_ws;                                    // 4092*512 f32
    unsigned short* core_bf = (unsigned short*)(core + (size_t)MROWS*DMODEL);
    unsigned short* pe_bf   = core_bf + (size_t)MROWS*DMODEL;      // 2045*512
    unsigned short* rk_bf   = pe_bf   + (size_t)RLEN*DMODEL;       // 2045*512
    unsigned short* av_bf   = rk_bf   + (size_t)RLEN*DMODEL;       // 4092*512
    unsigned short* big_bf  = av_bf   + (size_t)MROWS*DMODEL;      // 4092*2048
    unsigned short* qkvT = big_bf + (size_t)MROWS*DINNER;          // 1536*512
    unsigned short* rwT  = qkvT + (size_t)(3*DMODEL)*DMODEL;       // 512*512
    unsigned short* owT  = rwT  + (size_t)DMODEL*DMODEL;           // 512*512
    unsigned short* ff1T = owT  + (size_t)DMODEL*DMODEL;           // 2048*512
    unsigned short* ff2T = ff1T + (size_t)DINNER*DMODEL;           // 512*2048

    conv_pool_kernel<<<dim3(S_LEN, BATCH_N), 512, 0, stream>>>(sig, cw, cb, core, core_bf);
    posemb_kernel<<<RLEN, 512, 0, stream>>>(pe_bf);

    for (int l = 0; l < NLAYER; l++) {
        transpose_all_kernel<<<3328, 256, 0, stream>>>(
            qkv_w + (size_t)l*DMODEL*(3*DMODEL),
            r_w   + (size_t)l*DMODEL*DMODEL,
            o_w   + (size_t)l*DMODEL*DMODEL,
            ff1_w + (size_t)l*DMODEL*DINNER,
            ff2_w + (size_t)l*DINNER*DMODEL,
            qkvT, rwT, owT, ff1T, ff2T);

        // heads = core @ qkv_w AND rk = pe @ r_w, fused (one dispatch)
        gemm_qkvrk_kernel<<<dim3(32,32), 256, 0, stream>>>(
            core_bf, qkvT, big_bf, pe_bf, rwT, rk_bf);
        // attention (R8 + setprio)
        attn_mfma_kernel<<<dim3(32,32), 256, 0, stream>>>(big_bf, rk_bf, rwb, rrb, av_bf);
        // core += av @ o_w  (64x64: 8x64 = 512 blocks)
        gemm_mfma64<true,false,false,true,true><<<dim3(8,64), 256, 0, stream>>>(
            av_bf, owT, nullptr, core, core_bf, MROWS, DMODEL, DMODEL);
        // hid = relu(core @ ff1 + b) -> bf16  (128x64: 32x32 = 1024 blocks)
        gemm_mfma<64,false,true,true,false,true><<<dim3(32,32), 256, 0, stream>>>(
            core_bf, ff1T, ff1_b + (size_t)l*DINNER, nullptr, big_bf, MROWS, DINNER, DMODEL);
        // core += hid @ ff2 + b  (64x64: 8x64 = 512 blocks)
        gemm_mfma64<true,true,false,true,true><<<dim3(8,64), 256, 0, stream>>>(
            big_bf, ff2T, ff2_b + (size_t)l*DMODEL, core, core_bf, MROWS, DMODEL, DINNER);
    }

    final_kernel<<<40, 64, 0, stream>>>(core, fcw, fcb, out);
}

// Round 20
// 692.913 us; speedup vs baseline: 1.0065x; 1.0065x over previous
//
#include <hip/hip_runtime.h>
#include <math.h>

#define S_LEN   1023
#define BATCH_N 4
#define DMODEL  512
#define NHEAD   8
#define DHEAD   64
#define DINNER  2048
#define NLAYER  4
#define RAWLEN  8192
#define POOLW   8
#define KERNW   9
#define RLEN    (2*S_LEN-1)   /* 2045 */
#define MROWS   (S_LEN*BATCH_N) /* 4092 */

using bf16x8 = __attribute__((ext_vector_type(8))) short;
using f32x4  = __attribute__((ext_vector_type(4))) float;

__device__ __forceinline__ unsigned short f2bf(float f) {
    union { float f; unsigned int u; } v; v.f = f;
    unsigned int u = v.u;
    return (unsigned short)((u + 0x7fffu + ((u >> 16) & 1u)) >> 16);
}
__device__ __forceinline__ float bf2f(unsigned short h) {
    union { unsigned int u; float f; } v; v.u = ((unsigned int)h) << 16;
    return v.f;
}

// async 16B global -> LDS (dest = wave-uniform base + lane*16)
__device__ __forceinline__ void gload_lds16(const void* g, void* l) {
    using gvoid = const __attribute__((address_space(1))) void;
    using lvoid = __attribute__((address_space(3))) void;
    gvoid* gp = reinterpret_cast<gvoid*>(reinterpret_cast<unsigned long long>(g));
    lvoid* lp = reinterpret_cast<lvoid*>((unsigned int)reinterpret_cast<unsigned long long>(l));
    __builtin_amdgcn_global_load_lds(gp, lp, 16, 0, 0);
}

// ---------------- conv + relu + pool8 -> core f32 + bf16 ----------------
__global__ __launch_bounds__(512) void conv_pool_kernel(
    const float* __restrict__ sig, const float* __restrict__ cw,
    const float* __restrict__ cb, float* __restrict__ core,
    unsigned short* __restrict__ core_bf)
{
    int s = blockIdx.x, b = blockIdx.y, d = threadIdx.x;
    __shared__ float sseg[POOLW + KERNW - 1];
    if (d < POOLW + KERNW - 1) sseg[d] = sig[b*RAWLEN + s*POOLW + d];
    __syncthreads();
    float w[KERNW];
#pragma unroll
    for (int k = 0; k < KERNW; k++) w[k] = cw[k*DMODEL + d];
    float bias = cb[d];
    float acc = 0.f;
#pragma unroll
    for (int p = 0; p < POOLW; p++) {
        float c = bias;
#pragma unroll
        for (int k = 0; k < KERNW; k++) c = fmaf(sseg[p+k], w[k], c);
        acc += fmaxf(c, 0.f);
    }
    float v = acc * (1.0f/POOLW);
    core[(s*BATCH_N + b)*DMODEL + d] = v;
    core_bf[(s*BATCH_N + b)*DMODEL + d] = f2bf(v);
}

// ---------------- positional embedding -> bf16 ----------------
__global__ __launch_bounds__(512) void posemb_kernel(unsigned short* __restrict__ pe)
{
    int j = blockIdx.x, d = threadIdx.x;
    float pos = (float)(S_LEN - 1 - j);
    int i = (d < 256) ? d : d - 256;
    float invf = exp2f(-(float)i * (13.287712f/256.0f));
    float a = pos * invf;
    pe[j*DMODEL + d] = f2bf((d < 256) ? __sinf(a) : __cosf(a));
}

// ---------------- fused per-layer weight transposes: W[K][N] f32 -> Wt[N][K] bf16 ----------------
__global__ __launch_bounds__(256) void transpose_all_kernel(
    const float* __restrict__ qw, const float* __restrict__ rw,
    const float* __restrict__ ow, const float* __restrict__ f1,
    const float* __restrict__ f2,
    unsigned short* __restrict__ qT, unsigned short* __restrict__ rT,
    unsigned short* __restrict__ oT, unsigned short* __restrict__ f1T,
    unsigned short* __restrict__ f2T)
{
    int id = blockIdx.x;
    const float* W; unsigned short* Wt; int K, N, bx, by;
    if (id < 768)       { W = qw;  Wt = qT;  K = 512;  N = 1536; bx = id % 48; by = id / 48; }
    else if (id < 1024) { id -= 768;  W = rw;  Wt = rT;  K = 512;  N = 512;  bx = id % 16; by = id / 16; }
    else if (id < 1280) { id -= 1024; W = ow;  Wt = oT;  K = 512;  N = 512;  bx = id % 16; by = id / 16; }
    else if (id < 2304) { id -= 1280; W = f1;  Wt = f1T; K = 512;  N = 2048; bx = id % 64; by = id / 64; }
    else                { id -= 2304; W = f2;  Wt = f2T; K = 2048; N = 512;  bx = id % 16; by = id / 16; }

    __shared__ float L[32][33];
    int n0 = bx*32, k0 = by*32;
    int t = threadIdx.x;
    int kk = t>>3, nq = (t&7)*4;
    float4 v = *reinterpret_cast<const float4*>(&W[(size_t)(k0+kk)*N + n0 + nq]);
    L[kk][nq+0]=v.x; L[kk][nq+1]=v.y; L[kk][nq+2]=v.z; L[kk][nq+3]=v.w;
    __syncthreads();
    int nn = t>>3, kq = (t&7)*4;
    ushort4 o;
    o.x = f2bf(L[kq+0][nn]); o.y = f2bf(L[kq+1][nn]);
    o.z = f2bf(L[kq+2][nn]); o.w = f2bf(L[kq+3][nn]);
    *reinterpret_cast<ushort4*>(&Wt[(size_t)(n0+nn)*K + k0 + kq]) = o;
}

// ---------------- MFMA GEMM body (shared): A(MxK bf16) @ Bt(NxK bf16)^T -> C ----------------
template<int BN, bool ACCUM, bool BIAS, bool RELU, bool WF32, bool WBF>
__device__ __forceinline__ void gemm_body(
    const unsigned short* __restrict__ A, const unsigned short* __restrict__ Bt,
    const float* __restrict__ bias, float* __restrict__ C,
    unsigned short* __restrict__ Cb, int M, int N, int K, int bm, int bn,
    unsigned short* As, unsigned short* Bs)
{
    constexpr int MF = (BN == 128) ? 4 : 2;
    int tid = threadIdx.x, lane = tid & 63, wid = tid >> 6;

    f32x4 acc[MF][4];
#pragma unroll
    for (int m=0;m<MF;m++)
#pragma unroll
        for (int n=0;n<4;n++) acc[m][n] = (f32x4){0.f,0.f,0.f,0.f};

    int r0 = wid*16 + (lane>>2);
    int slot = (lane&3)*8;
    int ga0 = bm + r0;      if (ga0 > M-1) ga0 = M-1;
    int ga1 = bm + r0 + 64; if (ga1 > M-1) ga1 = M-1;
    const unsigned short* pA0 = A  + (size_t)ga0*K + slot;
    const unsigned short* pA1 = A  + (size_t)ga1*K + slot;
    const unsigned short* pB0 = Bt + (size_t)(bn + r0)*K + slot;
    const unsigned short* pB1 = (BN==128) ? Bt + (size_t)(bn + r0 + 64)*K + slot : nullptr;
    char* lA0 = (char*)As + wid*1024;
    char* lA1 = (char*)As + (wid+4)*1024;
    char* lB0 = (char*)Bs + wid*1024;
    char* lB1 = (char*)Bs + (wid+4)*1024;

    int ar = (BN==128 ? (wid>>1)*64 : wid*32) + (lane&15);
    int br = (BN==128 ? (wid&1)*64 : 0) + (lane&15);
    int kc = (lane>>4)*8;

    for (int k0 = 0; k0 < K; k0 += 32) {
        __syncthreads();
        gload_lds16(pA0, lA0);
        gload_lds16(pA1, lA1);
        gload_lds16(pB0, lB0);
        if (BN == 128) gload_lds16(pB1, lB1);
        pA0 += 32; pA1 += 32; pB0 += 32; if (BN==128) pB1 += 32;
        __syncthreads();
        bf16x8 a[MF], b[4];
#pragma unroll
        for (int m=0;m<MF;m++) a[m] = *reinterpret_cast<const bf16x8*>(&As[(ar + m*16)*32 + kc]);
#pragma unroll
        for (int n=0;n<4;n++) b[n] = *reinterpret_cast<const bf16x8*>(&Bs[(br + n*16)*32 + kc]);
#pragma unroll
        for (int m=0;m<MF;m++)
#pragma unroll
            for (int n=0;n<4;n++)
                acc[m][n] = __builtin_amdgcn_mfma_f32_16x16x32_bf16(a[m], b[n], acc[m][n], 0,0,0);
    }

    int col0 = bn + (BN==128 ? (wid&1)*64 : 0) + (lane&15);
    int rbase = bm + (BN==128 ? (wid>>1)*64 : wid*32) + (lane>>4)*4;
#pragma unroll
    for (int m=0;m<MF;m++) {
#pragma unroll
        for (int n=0;n<4;n++) {
            int col = col0 + n*16;
            float bv = BIAS ? bias[col] : 0.f;
#pragma unroll
            for (int r=0;r<4;r++) {
                int row = rbase + m*16 + r;
                if (row < M) {
                    float v = acc[m][n][r] + bv;
                    if (RELU) v = fmaxf(v, 0.f);
                    size_t off = (size_t)row*N + col;
                    if (ACCUM) v += C[off];
                    if (WF32) C[off] = v;
                    if (WBF)  Cb[off] = f2bf(v);
                }
            }
        }
    }
}

template<int BN, bool ACCUM, bool BIAS, bool RELU, bool WF32, bool WBF>
__global__ __launch_bounds__(256) void gemm_mfma(
    const unsigned short* __restrict__ A, const unsigned short* __restrict__ Bt,
    const float* __restrict__ bias, float* __restrict__ C,
    unsigned short* __restrict__ Cb, int M, int N, int K)
{
    __shared__ unsigned short As[128*32];
    __shared__ unsigned short Bs[BN*32];
    gemm_body<BN,ACCUM,BIAS,RELU,WF32,WBF>(A, Bt, bias, C, Cb, M, N, K,
        blockIdx.y*128, blockIdx.x*BN, As, Bs);
}

// fused qkv (x<24) + rk (x>=24, y<16) in one dispatch
__global__ __launch_bounds__(256) void gemm_qkvrk_kernel(
    const unsigned short* __restrict__ core_bf, const unsigned short* __restrict__ qkvT,
    unsigned short* __restrict__ heads,
    const unsigned short* __restrict__ pe_bf, const unsigned short* __restrict__ rwT,
    unsigned short* __restrict__ rk_bf)
{
    __shared__ unsigned short As[128*32];
    __shared__ unsigned short Bs[64*32];
    if (blockIdx.x < 24) {
        gemm_body<64,false,false,false,false,true>(core_bf, qkvT, nullptr, nullptr, heads,
            MROWS, 3*DMODEL, DMODEL, blockIdx.y*128, blockIdx.x*64, As, Bs);
    } else {
        if (blockIdx.y >= 16) return;
        gemm_body<64,false,false,false,false,true>(pe_bf, rwT, nullptr, nullptr, rk_bf,
            RLEN, DMODEL, DMODEL, blockIdx.y*128, (blockIdx.x-24)*64, As, Bs);
    }
}

// ---------------- 64x64-tile MFMA GEMM (narrow-N accumulating cases) ----------------
template<bool ACCUM, bool BIAS, bool RELU, bool WF32, bool WBF>
__global__ __launch_bounds__(256) void gemm_mfma64(
    const unsigned short* __restrict__ A, const unsigned short* __restrict__ Bt,
    const float* __restrict__ bias, float* __restrict__ C,
    unsigned short* __restrict__ Cb, int M, int N, int K)
{
    __shared__ unsigned short As[64*32];
    __shared__ unsigned short Bs[64*32];
    int bm = blockIdx.y * 64, bn = blockIdx.x * 64;
    int tid = threadIdx.x, lane = tid & 63, wid = tid >> 6;
    int wr = wid >> 1, wc = wid & 1;

    f32x4 acc[2][2];
#pragma unroll
    for (int m=0;m<2;m++)
#pragma unroll
        for (int n=0;n<2;n++) acc[m][n] = (f32x4){0.f,0.f,0.f,0.f};

    int r0 = wid*16 + (lane>>2);
    int slot = (lane&3)*8;
    int ga = bm + r0; if (ga > M-1) ga = M-1;
    const unsigned short* pA = A  + (size_t)ga*K + slot;
    const unsigned short* pB = Bt + (size_t)(bn + r0)*K + slot;
    char* lA = (char*)As + wid*1024;
    char* lB = (char*)Bs + wid*1024;

    int ar = wr*32 + (lane&15);
    int br = wc*32 + (lane&15);
    int kc = (lane>>4)*8;

    for (int k0 = 0; k0 < K; k0 += 32) {
        __syncthreads();
        gload_lds16(pA, lA);
        gload_lds16(pB, lB);
        pA += 32; pB += 32;
        __syncthreads();
        bf16x8 a[2], b[2];
#pragma unroll
        for (int m=0;m<2;m++) a[m] = *reinterpret_cast<const bf16x8*>(&As[(ar + m*16)*32 + kc]);
#pragma unroll
        for (int n=0;n<2;n++) b[n] = *reinterpret_cast<const bf16x8*>(&Bs[(br + n*16)*32 + kc]);
#pragma unroll
        for (int m=0;m<2;m++)
#pragma unroll
            for (int n=0;n<2;n++)
                acc[m][n] = __builtin_amdgcn_mfma_f32_16x16x32_bf16(a[m], b[n], acc[m][n], 0,0,0);
    }

    int col0 = bn + wc*32 + (lane&15);
    int rbase = bm + wr*32 + (lane>>4)*4;
#pragma unroll
    for (int m=0;m<2;m++) {
#pragma unroll
        for (int n=0;n<2;n++) {
            int col = col0 + n*16;
            float bv = BIAS ? bias[col] : 0.f;
#pragma unroll
            for (int r=0;r<4;r++) {
                int row = rbase + m*16 + r;
                if (row < M) {
                    float v = acc[m][n][r] + bv;
                    if (RELU) v = fmaxf(v, 0.f);
                    size_t off = (size_t)row*N + col;
                    if (ACCUM) v += C[off];
                    if (WF32) C[off] = v;
                    if (WBF)  Cb[off] = f2bf(v);
                }
            }
        }
    }
}

// ---------------- MFMA flash attention, all operands direct-from-global (R8 proven, verbatim) ----------------
#define TI 32
#define TJ 32
#define PSTR 40   /* bf16 row stride Pb */
#define ACSTR 36  /* f32 row stride Sac */
#define BDSTR 68  /* f32 row stride Sbd */

__global__ __launch_bounds__(256) void attn_mfma_kernel(
    const unsigned short* __restrict__ heads, // (S,B,1536) bf16
    const unsigned short* __restrict__ rk,    // (2045,512) bf16
    const float* __restrict__ rwb, const float* __restrict__ rrb,
    unsigned short* __restrict__ av)          // (S,B,512) bf16
{
    int i0 = blockIdx.x * TI;
    int bn = blockIdx.y; int b = bn >> 3, n = bn & 7;
    int tid = threadIdx.x, lane = tid & 63, wid = tid >> 6;
    int mi = wid >> 1;          // i-row block (0/1)
    int half = wid & 1;         // col-half assignment
    int kc = (lane>>4)*8;
    int l15 = lane & 15;

    __shared__ float Sac[TI*ACSTR];
    __shared__ float Sbd[TI*BDSTR];
    __shared__ unsigned short Pb[TI*PSTR];
    __shared__ float mrow[TI], lrow[TI], frow[TI];

    const int base0 = (S_LEN-1) - i0 - (TI-1);   // rk global row at window offset 0

    // ---- Q fragments direct from global, biases folded ----
    bf16x8 qwf0, qwf1, qrf0, qrf1;
    {
        int gi = i0 + mi*16 + l15; if (gi > S_LEN-1) gi = S_LEN-1;
        const unsigned short* qb = heads + (size_t)(gi*BATCH_N + b)*1536 + n*64;
        bf16x8 u0 = *reinterpret_cast<const bf16x8*>(qb + kc);
        bf16x8 u1 = *reinterpret_cast<const bf16x8*>(qb + 32 + kc);
#pragma unroll
        for (int e=0;e<8;e++) {
            float f0 = bf2f((unsigned short)u0[e]);
            float f1 = bf2f((unsigned short)u1[e]);
            qwf0[e] = (short)f2bf(f0 + rwb[n*64 + kc + e]);
            qrf0[e] = (short)f2bf(f0 + rrb[n*64 + kc + e]);
            qwf1[e] = (short)f2bf(f1 + rwb[n*64 + 32 + kc + e]);
            qrf1[e] = (short)f2bf(f1 + rrb[n*64 + 32 + kc + e]);
        }
    }
    if (tid < TI) { mrow[tid] = -1e30f; lrow[tid] = 0.f; }

    f32x4 Oa[2];
    Oa[0] = (f32x4){0.f,0.f,0.f,0.f};
    Oa[1] = (f32x4){0.f,0.f,0.f,0.f};

    int rw = mi*16 + (lane>>4)*4;

    for (int t = 0; t < 32; t++) {
        int j0 = t * TJ;
        __syncthreads();   // separates softmax(t-1) Sbd reads / PV(t-1) Pb reads from writes below

        // ---- AC scores: B-frag = K rows direct from global ----
        {
            int gj = j0 + half*16 + l15; if (gj > S_LEN-1) gj = S_LEN-1;
            const unsigned short* kb = heads + (size_t)(gj*BATCH_N + b)*1536 + 512 + n*64;
            bf16x8 kf0 = *reinterpret_cast<const bf16x8*>(kb + kc);
            bf16x8 kf1 = *reinterpret_cast<const bf16x8*>(kb + 32 + kc);
            f32x4 s = (f32x4){0.f,0.f,0.f,0.f};
            s = __builtin_amdgcn_mfma_f32_16x16x32_bf16(qwf0, kf0, s, 0,0,0);
            s = __builtin_amdgcn_mfma_f32_16x16x32_bf16(qwf1, kf1, s, 0,0,0);
            int ci = half*16 + l15;
#pragma unroll
            for (int r=0;r<4;r++) Sac[(rw+r)*ACSTR + ci] = s[r];
        }
        // ---- BD scores into rolling Sbd cache (phys col = off & 63) ----
        if (t == 0) {
#pragma unroll
            for (int nn=0;nn<2;nn++) {
                int w = (half*2+nn)*16 + l15;         // phys col == off at t=0
                int gr = base0 + w; gr = gr < 0 ? 0 : (gr > RLEN-1 ? RLEN-1 : gr);
                const unsigned short* rb = rk + (size_t)gr*DMODEL + n*64;
                bf16x8 rf0 = *reinterpret_cast<const bf16x8*>(rb + kc);
                bf16x8 rf1 = *reinterpret_cast<const bf16x8*>(rb + 32 + kc);
                f32x4 sb = (f32x4){0.f,0.f,0.f,0.f};
                sb = __builtin_amdgcn_mfma_f32_16x16x32_bf16(qrf0, rf0, sb, 0,0,0);
                sb = __builtin_amdgcn_mfma_f32_16x16x32_bf16(qrf1, rf1, sb, 0,0,0);
#pragma unroll
                for (int r=0;r<4;r++) Sbd[(rw+r)*BDSTR + w] = sb[r];
            }
        } else {
            int pblk = ((t & 1) ? 0 : 2) + half;      // 2 new 16-col blocks this tile
            int w = pblk*16 + l15;                    // phys col
            int off = 32*(t+1) + (w & 31);            // window offset for this phys col
            int gr = base0 + off; gr = gr < 0 ? 0 : (gr > RLEN-1 ? RLEN-1 : gr);
            const unsigned short* rb = rk + (size_t)gr*DMODEL + n*64;
            bf16x8 rf0 = *reinterpret_cast<const bf16x8*>(rb + kc);
            bf16x8 rf1 = *reinterpret_cast<const bf16x8*>(rb + 32 + kc);
            f32x4 sb = (f32x4){0.f,0.f,0.f,0.f};
            sb = __builtin_amdgcn_mfma_f32_16x16x32_bf16(qrf0, rf0, sb, 0,0,0);
            sb = __builtin_amdgcn_mfma_f32_16x16x32_bf16(qrf1, rf1, sb, 0,0,0);
#pragma unroll
            for (int r=0;r<4;r++) Sbd[(rw+r)*BDSTR + w] = sb[r];
        }
        __syncthreads();

        // ---- parallel online softmax: thread -> (row = tid>>3, 4 j at (tid&7)*4) ----
        {
            int r = tid>>3, seg = tid&7, jl = seg*4;
            float4 ac = *reinterpret_cast<const float4*>(&Sac[r*ACSTR + jl]);
            int cbase = 32*t + (TI-1) - r;    // phys col = (cbase + j) & 63
            float s0 = (ac.x + Sbd[r*BDSTR + ((cbase+jl+0)&63)]) * 0.125f;
            float s1 = (ac.y + Sbd[r*BDSTR + ((cbase+jl+1)&63)]) * 0.125f;
            float s2 = (ac.z + Sbd[r*BDSTR + ((cbase+jl+2)&63)]) * 0.125f;
            float s3 = (ac.w + Sbd[r*BDSTR + ((cbase+jl+3)&63)]) * 0.125f;
            int jg = j0 + jl;
            if (jg+0 >= S_LEN) s0 = -1e30f;
            if (jg+1 >= S_LEN) s1 = -1e30f;
            if (jg+2 >= S_LEN) s2 = -1e30f;
            if (jg+3 >= S_LEN) s3 = -1e30f;
            float tm = fmaxf(fmaxf(s0,s1), fmaxf(s2,s3));
            tm = fmaxf(tm, __shfl_xor(tm, 1));
            tm = fmaxf(tm, __shfl_xor(tm, 2));
            tm = fmaxf(tm, __shfl_xor(tm, 4));
            float mo = mrow[r];
            float mnew = fmaxf(mo, tm);
            float f = __expf(mo - mnew);
            float e0 = __expf(s0 - mnew), e1 = __expf(s1 - mnew);
            float e2 = __expf(s2 - mnew), e3 = __expf(s3 - mnew);
            float ssum = e0+e1+e2+e3;
            ssum += __shfl_xor(ssum, 1);
            ssum += __shfl_xor(ssum, 2);
            ssum += __shfl_xor(ssum, 4);
            if (seg == 0) {
                mrow[r] = mnew;
                lrow[r] = lrow[r]*f + ssum;
                frow[r] = f;
            }
            ushort4 pw;
            pw.x = f2bf(e0); pw.y = f2bf(e1); pw.z = f2bf(e2); pw.w = f2bf(e3);
            *reinterpret_cast<ushort4*>(&Pb[r*PSTR + jl]) = pw;
        }
        __syncthreads();

        // ---- PV: rescale O, then accumulate P @ V with V frags direct from global ----
        {
            float f0 = frow[rw+0], f1 = frow[rw+1], f2 = frow[rw+2], f3 = frow[rw+3];
#pragma unroll
            for (int nn=0;nn<2;nn++) {
                Oa[nn][0] *= f0; Oa[nn][1] *= f1; Oa[nn][2] *= f2; Oa[nn][3] *= f3;
            }
            bf16x8 pf = *reinterpret_cast<const bf16x8*>(&Pb[(mi*16 + l15)*PSTR + kc]);
            const unsigned short* vb = heads + 1024 + n*64;
#pragma unroll
            for (int nn=0;nn<2;nn++) {
                int d = (half*2+nn)*16 + l15;
                bf16x8 vf;
#pragma unroll
                for (int e=0;e<8;e++) {
                    int gj = j0 + kc + e; if (gj > S_LEN-1) gj = S_LEN-1;
                    vf[e] = (short)vb[(size_t)(gj*BATCH_N + b)*1536 + d];
                }
                Oa[nn] = __builtin_amdgcn_mfma_f32_16x16x32_bf16(pf, vf, Oa[nn], 0,0,0);
            }
        }
    }
    __syncthreads();

    // ---- epilogue ----
    {
        float linv[4];
#pragma unroll
        for (int r=0;r<4;r++) linv[r] = 1.0f / lrow[rw+r];
#pragma unroll
        for (int nn=0;nn<2;nn++) {
            int d = (half*2+nn)*16 + l15;
#pragma unroll
            for (int r=0;r<4;r++) {
                int gi = i0 + rw + r;
                if (gi < S_LEN)
                    av[(size_t)(gi*BATCH_N + b)*DMODEL + n*64 + d] = f2bf(Oa[nn][r]*linv[r]);
            }
        }
    }
}

// ---------------- final classifier (f32) ----------------
__global__ __launch_bounds__(64) void final_kernel(
    const float* __restrict__ core, const float* __restrict__ fcw,
    const float* __restrict__ fcb, float* __restrict__ out)
{
    int idx = blockIdx.x;
    int b = idx / 10, c = idx % 10;
    int lane = threadIdx.x;
    const float* row = &core[(size_t)((S_LEN-1)*BATCH_N + b)*DMODEL];
    float acc = 0.f;
    for (int d = lane; d < DMODEL; d += 64)
        acc = fmaf(row[d], fcw[d*10 + c], acc);
#pragma unroll
    for (int off = 32; off; off >>= 1) acc += __shfl_xor(acc, off);
    if (lane == 0) out[b*10 + c] = acc + fcb[c];
}

extern "C" void kernel_launch(void* const* d_in, const int* in_sizes, int n_in,
                              void* d_out, int out_size, void* d_ws, size_t ws_size,
                              hipStream_t stream)
{
    const float* sig   = (const float*)d_in[0];
    const float* cw    = (const float*)d_in[1];
    const float* cb    = (const float*)d_in[2];
    const float* qkv_w = (const float*)d_in[3];
    const float* r_w   = (const float*)d_in[4];
    const float* o_w   = (const float*)d_in[5];
    const float* ff1_w = (const float*)d_in[6];
    const float* ff1_b = (const float*)d_in[7];
    const float* ff2_w = (const float*)d_in[8];
    const float* ff2_b = (const float*)d_in[9];
    const float* rwb   = (const float*)d_in[10];
    const float* rrb   = (const float*)d_in[11];
    const float* fcw   = (const float*)d_in[12];
    const float* fcb   = (const float*)d_in[13];
    float* out = (float*)d_out;

    // workspace layout
    float* core = (float*)d_ws;                                    // 4092*512 f32
    unsigned short* core_bf = (unsigned short*)(core + (size_t)MROWS*DMODEL);
    unsigned short* pe_bf   = core_bf + (size_t)MROWS*DMODEL;      // 2045*512
    unsigned short* rk_bf   = pe_bf   + (size_t)RLEN*DMODEL;       // 2045*512
    unsigned short* av_bf   = rk_bf   + (size_t)RLEN*DMODEL;       // 4092*512
    unsigned short* big_bf  = av_bf   + (size_t)MROWS*DMODEL;      // 4092*2048
    unsigned short* qkvT = big_bf + (size_t)MROWS*DINNER;          // 1536*512
    unsigned short* rwT  = qkvT + (size_t)(3*DMODEL)*DMODEL;       // 512*512
    unsigned short* owT  = rwT  + (size_t)DMODEL*DMODEL;           // 512*512
    unsigned short* ff1T = owT  + (size_t)DMODEL*DMODEL;           // 2048*512
    unsigned short* ff2T = ff1T + (size_t)DINNER*DMODEL;           // 512*2048

    conv_pool_kernel<<<dim3(S_LEN, BATCH_N), 512, 0, stream>>>(sig, cw, cb, core, core_bf);
    posemb_kernel<<<RLEN, 512, 0, stream>>>(pe_bf);

    for (int l = 0; l < NLAYER; l++) {
        transpose_all_kernel<<<3328, 256, 0, stream>>>(
            qkv_w + (size_t)l*DMODEL*(3*DMODEL),
            r_w   + (size_t)l*DMODEL*DMODEL,
            o_w   + (size_t)l*DMODEL*DMODEL,
            ff1_w + (size_t)l*DMODEL*DINNER,
            ff2_w + (size_t)l*DINNER*DMODEL,
            qkvT, rwT, owT, ff1T, ff2T);

        // heads = core @ qkv_w AND rk = pe @ r_w, fused (one dispatch)
        gemm_qkvrk_kernel<<<dim3(32,32), 256, 0, stream>>>(
            core_bf, qkvT, big_bf, pe_bf, rwT, rk_bf);
        // attention (R8 proven, verbatim)
        attn_mfma_kernel<<<dim3(32,32), 256, 0, stream>>>(big_bf, rk_bf, rwb, rrb, av_bf);
        // core += av @ o_w  (64x64: 8x64 = 512 blocks)
        gemm_mfma64<true,false,false,true,true><<<dim3(8,64), 256, 0, stream>>>(
            av_bf, owT, nullptr, core, core_bf, MROWS, DMODEL, DMODEL);
        // hid = relu(core @ ff1 + b) -> bf16  (128x64: 32x32 = 1024 blocks)
        gemm_mfma<64,false,true,true,false,true><<<dim3(32,32), 256, 0, stream>>>(
            core_bf, ff1T, ff1_b + (size_t)l*DINNER, nullptr, big_bf, MROWS, DINNER, DMODEL);
        // core += hid @ ff2 + b  (64x64: 8x64 = 512 blocks)
        gemm_mfma64<true,true,false,true,true><<<dim3(8,64), 256, 0, stream>>>(
            big_bf, ff2T, ff2_b + (size_t)l*DMODEL, core, core_bf, MROWS, DMODEL, DINNER);
    }

    final_kernel<<<40, 64, 0, stream>>>(core, fcw, fcb, out);
}